// Round 7
// baseline (545.549 us; speedup 1.0000x reference)
//
#include <hip/hip_runtime.h>
#include <stdint.h>

#define TOKENS 4096
#define HS 1024
#define FFN 4096
#define NE 8
#define CAP 512

typedef __attribute__((ext_vector_type(8))) __bf16 v8bf;
typedef __attribute__((ext_vector_type(4))) float v4f;
typedef __attribute__((ext_vector_type(8))) unsigned short v8us;
typedef __attribute__((ext_vector_type(4))) unsigned short v4us;
typedef __attribute__((ext_vector_type(4))) unsigned int v4u;

typedef __attribute__((address_space(1))) const void AS1cvoid;
typedef __attribute__((address_space(3))) void AS3void;

// round-to-nearest-even fp32 -> bf16 bits
__device__ __forceinline__ unsigned short f2bf(float f) {
    union { float f; unsigned int u; } c; c.f = f;
    unsigned int u = c.u;
    unsigned int r = (u + 0x7fffu + ((u >> 16) & 1u)) >> 16;
    return (unsigned short)r;
}

// async global->LDS, 16B per lane. LDS dest must be wave-uniform base; HW adds lane*16.
__device__ __forceinline__ void gload16(const void* g, void* l) {
    __builtin_amdgcn_global_load_lds((AS1cvoid*)g, (AS3void*)l, 16, 0, 0);
}

// ===================================== fused prep: transpose+cvt (both weights) + router
// blocks 0..16383: transpose, 64x64 f32 tile per block.
//   LDS: packed-u32 column-major, stride 32 words, XOR-swizzled:
//     addr32(c,j) = c*32 + (j ^ (((c>>2)&7)<<2)); word j of col c = rows {2j,2j+1} bf16.
//   Write phase banks 2-way (free); read phase ds_read_b128 conflict-free; XOR
//   preserves 4-word alignment so all b128 reads are 16B-aligned.
// blocks 16384..17407: router top-2 + x->bf16 (rw read direct from L2; no LDS stage).
__global__ __launch_bounds__(256) void prep_kernel(
    const float* __restrict__ w1, unsigned short* __restrict__ w1t,
    const float* __restrict__ w2, unsigned short* __restrict__ w2t,
    const float* __restrict__ x, const float* __restrict__ rw,
    unsigned short* __restrict__ xb,
    int* __restrict__ topk_e, float* __restrict__ topk_w) {
    __shared__ __align__(16) unsigned int cm[64 * 32];   // 8 KB
    const int bid = blockIdx.x;
    const int t = threadIdx.x;

    if (bid < 16384) {
        // ---------------- transpose+cvt path
        const int half = bid >> 13;          // 0: w1, 1: w2
        const int e = bid & 7;
        const int rest = (bid >> 3) & 1023;  // 1024 tiles per (e,half)
        int R, C, rt, ct;
        const float* inp;
        unsigned short* outp;
        if (half == 0) { R = HS; C = FFN; rt = rest >> 6; ct = rest & 63; inp = w1; outp = w1t; }
        else           { R = FFN; C = HS; rt = rest >> 4; ct = rest & 15; inp = w2; outp = w2t; }
        const size_t esz = (size_t)R * C;
        const float* ine = inp + (size_t)e * esz;
        unsigned short* oute = outp + (size_t)e * esz;
        const int r0 = rt * 64, c0 = ct * 64;

        const int rg = t >> 4;               // 0..15 row-pair group
        const int cq = (t & 15) * 4;         // col base (x4)
#pragma unroll
        for (int p = 0; p < 2; ++p) {
            const int re = p * 32 + rg * 2;  // even row within tile
            float4 f0 = *(const float4*)&ine[(size_t)(r0 + re) * C + c0 + cq];
            float4 f1 = *(const float4*)&ine[(size_t)(r0 + re + 1) * C + c0 + cq];
            const float* a0 = (const float*)&f0;
            const float* a1 = (const float*)&f1;
            const int j = p * 16 + rg;       // word index 0..31
#pragma unroll
            for (int k = 0; k < 4; ++k) {
                const int c = cq + k;
                cm[c * 32 + (j ^ (((c >> 2) & 7) << 2))] =
                    ((unsigned int)f2bf(a1[k]) << 16) | f2bf(a0[k]);
            }
        }
        __syncthreads();
        const int rq = (t & 7) * 4;          // word base -> rows 8*(t&7)..+7
#pragma unroll
        for (int pass = 0; pass < 2; ++pass) {
            const int c = pass * 32 + (t >> 3);
            v4u v = *(const v4u*)&cm[c * 32 + (rq ^ (((c >> 2) & 7) << 2))];
            *(v4u*)&oute[(size_t)(c0 + c) * R + r0 + (t & 7) * 8] = v;
        }
    } else {
        // ---------------- router path (4 tokens per block)
        const int lane = t & 63, wave = t >> 6;
        const int tok = (bid - 16384) * 4 + wave;
        const float4* xr4 = (const float4*)(x + (size_t)tok * HS);
        const float4* rw4 = (const float4*)rw;   // rw[h][e]: row h = 2 float4
        unsigned short* xbr = xb + (size_t)tok * HS;
        float acc[NE] = {0.f, 0.f, 0.f, 0.f, 0.f, 0.f, 0.f, 0.f};
#pragma unroll
        for (int it = 0; it < 4; ++it) {
            float4 f = xr4[it * 64 + lane];
            const float* fa = (const float*)&f;
            int h0 = (it * 64 + lane) * 4;
            v4us pk;
#pragma unroll
            for (int k = 0; k < 4; ++k) {
                float fv = fa[k];
                float4 ra = rw4[(h0 + k) * 2];
                float4 rb = rw4[(h0 + k) * 2 + 1];
                acc[0] += fv * ra.x; acc[1] += fv * ra.y; acc[2] += fv * ra.z; acc[3] += fv * ra.w;
                acc[4] += fv * rb.x; acc[5] += fv * rb.y; acc[6] += fv * rb.z; acc[7] += fv * rb.w;
                pk[k] = f2bf(fv);
            }
            *(v4us*)&xbr[h0] = pk;
        }
#pragma unroll
        for (int e = 0; e < NE; ++e) {
#pragma unroll
            for (int off = 32; off > 0; off >>= 1)
                acc[e] += __shfl_down(acc[e], off, 64);
        }
        if (lane == 0) {
            int b1 = 0; float v1 = acc[0];
#pragma unroll
            for (int e = 1; e < NE; ++e) if (acc[e] > v1) { v1 = acc[e]; b1 = e; }
            int b2 = -1; float v2 = -3.4e38f;
#pragma unroll
            for (int e = 0; e < NE; ++e)
                if (e != b1 && acc[e] > v2) { v2 = acc[e]; b2 = e; }
            float s = 0.f;
#pragma unroll
            for (int e = 0; e < NE; ++e) s += expf(acc[e] - v1);
            float inv = 1.f / s;
            topk_e[tok * 2] = b1;
            topk_e[tok * 2 + 1] = b2;
            topk_w[tok * 2] = inv;
            topk_w[tok * 2 + 1] = expf(v2 - v1) * inv;
        }
    }
}

// ------------------------------------------------- dispatch: stable capped lists
__global__ void dispatch_kernel(const int* __restrict__ topk_e,
                                const float* __restrict__ topk_w,
                                int* __restrict__ comb_tok,
                                float* __restrict__ comb_gate,
                                int* __restrict__ slot_of) {
    __shared__ int hist[1024 * 8];
    __shared__ int c0[NE];
    __shared__ int tpe_s[NE];
    const int tid = threadIdx.x;   // 1024
    for (int i = tid; i < NE * 1024; i += 1024) { comb_tok[i] = 0; comb_gate[i] = 0.f; }

    for (int k = 0; k < 2; ++k) {
        int cnt[NE];
#pragma unroll
        for (int e = 0; e < NE; ++e) cnt[e] = 0;
        int myexp[4];
#pragma unroll
        for (int j = 0; j < 4; ++j) {
            int t = tid * 4 + j;
            int ex = topk_e[t * 2 + k];
            myexp[j] = ex;
            cnt[ex]++;
        }
#pragma unroll
        for (int e = 0; e < NE; ++e) hist[tid * 8 + e] = cnt[e];
        __syncthreads();
        for (int off = 1; off < 1024; off <<= 1) {
            int v[NE];
#pragma unroll
            for (int e = 0; e < NE; ++e) {
                v[e] = hist[tid * 8 + e];
                if (tid >= off) v[e] += hist[(tid - off) * 8 + e];
            }
            __syncthreads();
#pragma unroll
            for (int e = 0; e < NE; ++e) hist[tid * 8 + e] = v[e];
            __syncthreads();
        }
        int base[NE];
#pragma unroll
        for (int e = 0; e < NE; ++e) base[e] = hist[tid * 8 + e] - cnt[e];
        if (tid == 1023) {
#pragma unroll
            for (int e = 0; e < NE; ++e) tpe_s[e] = hist[1023 * 8 + e];
        }
        __syncthreads();
        if (k == 0 && tid < NE) c0[tid] = min(tpe_s[tid], CAP);
        __syncthreads();
#pragma unroll
        for (int j = 0; j < 4; ++j) {
            int t = tid * 4 + j;
            int ex = myexp[j];
            int p = base[ex]++;
            int sl = -1;
            if (p < CAP) {
                int idx = (k == 0) ? p : (c0[ex] + p);
                sl = ex * 1024 + idx;
                comb_tok[sl] = t;
                comb_gate[sl] = topk_w[t * 2 + k];
            }
            slot_of[t * 2 + k] = sl;
        }
        __syncthreads();
    }
}

// =================================================================================
// 8-phase 256x256 BK=64 pipelined GEMM core (T2 swizzle + T3/T4 counted vmcnt + T5)
// LDS 128 KB: A0 | B0 | A1 | B1, each 256 rows x 64 cols bf16 (128 B rows).
// Swizzle: 16B chunk c of row r stored at chunk c ^ (r & 7)  (involution);
// pre-applied on the GLOBAL source (global_load_lds writes linearly), applied
// again on the read side.
// Fragment reads are plain C++ v8bf loads: dataflow deps order them vs MFMA, and
// the "memory"-clobbered waitcnt asms anchor them vs the LDS-DMA staging. NO
// sched_barrier(0) anywhere: m141 measured order-pinning at 510 vs 874 TF.
// =================================================================================
#define BARR __builtin_amdgcn_s_barrier()
#define LGK0 asm volatile("s_waitcnt lgkmcnt(0)" ::: "memory")
#define VMC4 asm volatile("s_waitcnt vmcnt(4)" ::: "memory")
#define VMC0 asm volatile("s_waitcnt vmcnt(0)" ::: "memory")

// region offsets: ushort index (U) and bytes (B)
#define A0U 0
#define B0U 16384
#define A1U 32768
#define B1U 49152
#define A0B 0
#define B0B 32768
#define A1B 65536
#define B1B 98304

// stage one half-tile (128 rows x 64 cols): 2 gload16 per thread, linear LDS dest
#define STAGE2(P0, P1, LBYTE, KT) do { \
    gload16((P0) + (size_t)(KT) * 64, (char*)lds + (LBYTE) + wv * 2048); \
    gload16((P1) + (size_t)(KT) * 64, (char*)lds + (LBYTE) + wv * 2048 + 1024); } while (0)

// A fragment reads: 8 x v8bf loads (compiler emits ds_read_b128)
#define PH_READ_A(REGU, MQ) do { \
    _Pragma("unroll") \
    for (int i2 = 0; i2 < 4; ++i2) { \
        a[i2][0] = *(const v8bf*)&lds[(REGU) + arow + (MQ) * 4096 + i2 * 1024 + axk0]; \
        a[i2][1] = *(const v8bf*)&lds[(REGU) + arow + (MQ) * 4096 + i2 * 1024 + axk1]; \
    } } while (0)

// B fragment reads: 4 x v8bf loads
#define PH_READ_B(REGU, NQ) do { \
    _Pragma("unroll") \
    for (int j2 = 0; j2 < 2; ++j2) { \
        b[(NQ) * 2 + j2][0] = *(const v8bf*)&lds[(REGU) + brow + ((NQ) * 2 + j2) * 1024 + axk0]; \
        b[(NQ) * 2 + j2][1] = *(const v8bf*)&lds[(REGU) + brow + ((NQ) * 2 + j2) * 1024 + axk1]; \
    } } while (0)

#define PH_MFMA(MQ, NQ) do { \
    __builtin_amdgcn_s_setprio(1); \
    _Pragma("unroll") \
    for (int ks = 0; ks < 2; ++ks) \
    _Pragma("unroll") \
    for (int i2 = 0; i2 < 4; ++i2) \
    _Pragma("unroll") \
    for (int j2 = 0; j2 < 2; ++j2) \
        acc[(MQ) * 4 + i2][(NQ) * 2 + j2] = __builtin_amdgcn_mfma_f32_16x16x32_bf16( \
            a[i2][ks], b[(NQ) * 2 + j2][ks], acc[(MQ) * 4 + i2][(NQ) * 2 + j2], 0, 0, 0); \
    __builtin_amdgcn_s_setprio(0); } while (0)

// Schedule per iter t (K-tiles 2t in buf0, 2t+1 in buf1; prefetch 2t+2/2t+3).
// vmcnt ledger: 12 in flight at each VMC4 -> waits for the oldest 8 (the two
// half-tile pairs consumed in the next 4 phases), leaves newest 4 in flight.
// Each region's last reader phase precedes its re-stage phase across a barrier
// pair (no WAR hazard).
#define MOE_PIPE(NITER_) do { \
    STAGE2(pA00, pA01, A0B, 0); \
    STAGE2(pA10, pA11, A0B + 16384, 0); \
    STAGE2(pB00, pB01, B0B, 0); \
    STAGE2(pB10, pB11, B0B + 16384, 0); \
    STAGE2(pB00, pB01, B1B, 1); \
    STAGE2(pB10, pB11, B1B + 16384, 1); \
    VMC4; BARR; \
    for (int t = 0; t < (NITER_); ++t) { \
        const int T1k = 2 * t + 1, T2k = 2 * t + 2, T3k = 2 * t + 3; \
        const bool more = (t + 1 < (NITER_)); \
        PH_READ_A(A0U, 0); PH_READ_B(B0U, 0); \
        STAGE2(pA00, pA01, A1B, T1k); \
        BARR; LGK0; PH_MFMA(0, 0); BARR; \
        PH_READ_B(B0U, 1); \
        STAGE2(pA10, pA11, A1B + 16384, T1k); \
        BARR; LGK0; PH_MFMA(0, 1); BARR; \
        PH_READ_A(A0U, 1); \
        if (more) STAGE2(pB00, pB01, B0B, T2k); \
        BARR; LGK0; PH_MFMA(1, 0); BARR; \
        if (more) { STAGE2(pB10, pB11, B0B + 16384, T2k); VMC4; } else { VMC0; } \
        BARR; PH_MFMA(1, 1); BARR; \
        PH_READ_A(A1U, 0); PH_READ_B(B1U, 0); \
        if (more) STAGE2(pA00, pA01, A0B, T2k); \
        BARR; LGK0; PH_MFMA(0, 0); BARR; \
        PH_READ_B(B1U, 1); \
        if (more) STAGE2(pA10, pA11, A0B + 16384, T2k); \
        BARR; LGK0; PH_MFMA(0, 1); BARR; \
        PH_READ_A(A1U, 1); \
        if (more) STAGE2(pB00, pB01, B1B, T3k); \
        BARR; LGK0; PH_MFMA(1, 0); BARR; \
        if (more) { STAGE2(pB10, pB11, B1B + 16384, T3k); VMC4; } else { VMC0; } \
        BARR; PH_MFMA(1, 1); BARR; \
    } } while (0)

// ------------------------------------------------- GEMM1: h = gelu(gather(x) @ W1e)
// grid 512: id&7 = expert (XCD-affine); rest: mt 0..3 (slot/256), nt 0..15 (ffn/256)
__global__ __launch_bounds__(512, 2) void gemm1_kernel(
    const unsigned short* __restrict__ xb,      // [TOKENS][HS] bf16
    const unsigned short* __restrict__ w1t,     // [E][FFN][HS] bf16
    const int* __restrict__ comb_tok,           // [E][1024]
    unsigned short* __restrict__ h)             // [E][1024][FFN] bf16
{
    __shared__ __align__(16) unsigned short lds[65536];   // 128 KB
    const int id = blockIdx.x;
    const int e = id & 7;
    const int rest = id >> 3;
    const int mt = rest & 3;
    const int nt = rest >> 2;          // 0..15
    const int tid = threadIdx.x;
    const int wv = tid >> 6;           // wave 0..7
    const int l = tid & 63;
    const int m = l & 15;
    const int quad = l >> 4;
    const int wr = wv >> 2;            // 0..1 -> 128 rows
    const int wc = wv & 3;             // 0..3 -> 64 cols
    const int l3 = l >> 3;             // 0..7
    const int cgs = ((l & 7) ^ l3) * 8;   // pre-swizzled global chunk (elems)

    // staging rows (within 256-row tile): r(h,j) = h*128 + wv*16 + j*8 + l3
    const int r00 = wv * 16 + l3, r01 = r00 + 8, r10 = r00 + 128, r11 = r01 + 128;
    const int tbase = e * 1024 + mt * 256;
    const unsigned short* pA00 = xb + (size_t)comb_tok[tbase + r00] * HS + cgs;
    const unsigned short* pA01 = xb + (size_t)comb_tok[tbase + r01] * HS + cgs;
    const unsigned short* pA10 = xb + (size_t)comb_tok[tbase + r10] * HS + cgs;
    const unsigned short* pA11 = xb + (size_t)comb_tok[tbase + r11] * HS + cgs;
    const unsigned short* wbp = w1t + (size_t)e * FFN * HS + (size_t)(nt * 256) * HS + cgs;
    const unsigned short* pB00 = wbp + (size_t)r00 * HS;
    const unsigned short* pB01 = wbp + (size_t)r01 * HS;
    const unsigned short* pB10 = wbp + (size_t)r10 * HS;
    const unsigned short* pB11 = wbp + (size_t)r11 * HS;

    // fragment-read bases (ushort idx within region) + swizzled chunk offsets
    const int arow = (wr * 128 + m) * 64;
    const int brow = (wc * 64 + m) * 64;
    const int axk0 = (quad ^ (m & 7)) * 8;
    const int axk1 = ((quad + 4) ^ (m & 7)) * 8;

    v4f acc[8][4];
#pragma unroll
    for (int i = 0; i < 8; ++i)
#pragma unroll
        for (int j = 0; j < 4; ++j) acc[i][j] = (v4f)(0.f);
    v8bf a[4][2], b[4][2];

    MOE_PIPE(8);   // 16 K-tiles of 64 (K = HS = 1024)

    // epilogue: gelu -> per-wave swizzled LDS repack -> 16B global stores
    unsigned short* us = lds + wv * 8192;    // 128x64 bf16 slice per wave
#pragma unroll
    for (int i = 0; i < 8; ++i)
#pragma unroll
        for (int j = 0; j < 4; ++j) {
            v4f v = acc[i][j];
#pragma unroll
            for (int r = 0; r < 4; ++r) {
                int row = i * 16 + quad * 4 + r;
                int col = j * 16 + m;
                float val = v[r];
                float inner = 0.7978845608028654f * (val + 0.044715f * val * val * val);
                float g = val / (1.f + __expf(-2.f * inner));   // val*sigmoid(2*inner)
                us[row * 64 + (((col >> 3) ^ (row & 7)) * 8) + (col & 7)] = f2bf(g);
            }
        }
    __syncthreads();
    unsigned short* hb = h + (size_t)e * 1024 * FFN + (size_t)(mt * 256 + wr * 128) * FFN
                         + nt * 256 + wc * 64;
    const int chl = l & 7;
#pragma unroll
    for (int p = 0; p < 16; ++p) {
        int row = p * 8 + l3;
        v8us v = *(const v8us*)&us[row * 64 + ((chl ^ l3) * 8)];
        *(v8us*)&hb[(size_t)row * FFN + chl * 8] = v;
    }
}

// ------------------------------------------------- GEMM2: y_ks[slot] = gate * (h @ W2e)_Khalf
// grid 256: id&7 = expert (XCD-affine); rest: mt 0..3, nt 0..3, ks 0..1 (split-K)
__global__ __launch_bounds__(512, 2) void gemm2_kernel(
    const unsigned short* __restrict__ hbuf,    // [E][1024][FFN] bf16
    const unsigned short* __restrict__ w2t,     // [E][HS][FFN] bf16
    const float* __restrict__ comb_gate,
    float* __restrict__ y0,                     // [E*1024][HS] fp32 (K half 0)
    float* __restrict__ y1)                     // [E*1024][HS] fp32 (K half 1)
{
    __shared__ __align__(16) unsigned short lds[65536];   // 128 KB
    const int id = blockIdx.x;
    const int e = id & 7;
    const int rest = id >> 3;
    const int mt = rest & 3;
    const int nt = (rest >> 2) & 3;
    const int ks = rest >> 4;
    const int tid = threadIdx.x;
    const int wv = tid >> 6;
    const int l = tid & 63;
    const int m = l & 15;
    const int quad = l >> 4;
    const int wr = wv >> 2;
    const int wc = wv & 3;
    const int l3 = l >> 3;
    const int cgs = ((l & 7) ^ l3) * 8;

    const int r00 = wv * 16 + l3, r01 = r00 + 8, r10 = r00 + 128, r11 = r01 + 128;
    const unsigned short* ha = hbuf + (size_t)e * 1024 * FFN + (size_t)(mt * 256) * FFN
                               + ks * 2048 + cgs;
    const unsigned short* pA00 = ha + (size_t)r00 * FFN;
    const unsigned short* pA01 = ha + (size_t)r01 * FFN;
    const unsigned short* pA10 = ha + (size_t)r10 * FFN;
    const unsigned short* pA11 = ha + (size_t)r11 * FFN;
    const unsigned short* wbp = w2t + (size_t)e * HS * FFN + (size_t)(nt * 256) * FFN
                                + ks * 2048 + cgs;
    const unsigned short* pB00 = wbp + (size_t)r00 * FFN;
    const unsigned short* pB01 = wbp + (size_t)r01 * FFN;
    const unsigned short* pB10 = wbp + (size_t)r10 * FFN;
    const unsigned short* pB11 = wbp + (size_t)r11 * FFN;

    const int arow = (wr * 128 + m) * 64;
    const int brow = (wc * 64 + m) * 64;
    const int axk0 = (quad ^ (m & 7)) * 8;
    const int axk1 = ((quad + 4) ^ (m & 7)) * 8;

    v4f acc[8][4];
#pragma unroll
    for (int i = 0; i < 8; ++i)
#pragma unroll
        for (int j = 0; j < 4; ++j) acc[i][j] = (v4f)(0.f);
    v8bf a[4][2], b[4][2];

    MOE_PIPE(16);   // 32 K-tiles of 64 (K half = 2048)

    // epilogue: gated fp32 stores (64B segments per 16-lane group)
    float* yb = (ks ? y1 : y0) + (size_t)e * 1024 * HS;
    const int rbase = mt * 256 + wr * 128;
    const int cbase = nt * 256 + wc * 64;
#pragma unroll
    for (int i = 0; i < 8; ++i) {
        float gate_r[4];
        int row_r[4];
#pragma unroll
        for (int r = 0; r < 4; ++r) {
            row_r[r] = rbase + i * 16 + quad * 4 + r;
            gate_r[r] = comb_gate[e * 1024 + row_r[r]];
        }
#pragma unroll
        for (int j = 0; j < 4; ++j) {
            v4f v = acc[i][j];
#pragma unroll
            for (int r = 0; r < 4; ++r)
                yb[(size_t)row_r[r] * HS + cbase + j * 16 + m] = gate_r[r] * v[r];
        }
    }
}

// --------------------------- combine: out = bias + sum over k,ks of y_ks[slot_k]
__global__ void combine_kernel(const float* __restrict__ y0, const float* __restrict__ y1,
                               const int* __restrict__ slot_of,
                               const float* __restrict__ bias,
                               float* __restrict__ out) {
    int t = blockIdx.x;            // token
    int c = threadIdx.x;           // float4 lane, 256
    const float4* y04 = (const float4*)y0;
    const float4* y14 = (const float4*)y1;
    float4 a = ((const float4*)bias)[c];
    int s0 = slot_of[t * 2];
    int s1 = slot_of[t * 2 + 1];
    if (s0 >= 0) {
        float4 u = y04[(size_t)s0 * 256 + c];
        float4 v = y14[(size_t)s0 * 256 + c];
        a.x += u.x + v.x; a.y += u.y + v.y; a.z += u.z + v.z; a.w += u.w + v.w;
    }
    if (s1 >= 0) {
        float4 u = y04[(size_t)s1 * 256 + c];
        float4 v = y14[(size_t)s1 * 256 + c];
        a.x += u.x + v.x; a.y += u.y + v.y; a.z += u.z + v.z; a.w += u.w + v.w;
    }
    ((float4*)out)[(size_t)t * 256 + c] = a;
}

// ---------------------------------------------------------------------- launch
extern "C" void kernel_launch(void* const* d_in, const int* in_sizes, int n_in,
                              void* d_out, int out_size, void* d_ws, size_t ws_size,
                              hipStream_t stream) {
    (void)in_sizes; (void)n_in; (void)out_size; (void)ws_size;
    const float* x    = (const float*)d_in[0];
    const float* rw   = (const float*)d_in[1];
    const float* w1   = (const float*)d_in[2];
    const float* w2   = (const float*)d_in[3];
    const float* bias = (const float*)d_in[4];
    float* out = (float*)d_out;

    char* p = (char*)d_ws;
    unsigned short* w1t  = (unsigned short*)p; p += (size_t)NE * FFN * HS * 2;   // 64 MB (dead after gemm1)
    unsigned short* w2t  = (unsigned short*)p; p += (size_t)NE * HS * FFN * 2;   // 64 MB
    unsigned short* xb   = (unsigned short*)p; p += (size_t)TOKENS * HS * 2;     // 8 MB
    unsigned short* hbuf = (unsigned short*)p; p += (size_t)NE * 1024 * FFN * 2; // 64 MB
    float* ybuf0     = (float*)p; p += (size_t)NE * 1024 * HS * 4;               // 32 MB
    int*   topk_e    = (int*)p;   p += (size_t)TOKENS * 2 * 4;
    float* topk_w    = (float*)p; p += (size_t)TOKENS * 2 * 4;
    int*   comb_tok  = (int*)p;   p += (size_t)NE * 1024 * 4;
    float* comb_gate = (float*)p; p += (size_t)NE * 1024 * 4;
    int*   slot_of   = (int*)p;   p += (size_t)TOKENS * 2 * 4;
    float* ybuf1 = (float*)w1t;   // alias: w1t dead once gemm1 completes

    prep_kernel<<<17408, 256, 0, stream>>>(w1, w1t, w2, w2t, x, rw, xb, topk_e, topk_w);
    dispatch_kernel<<<1, 1024, 0, stream>>>(topk_e, topk_w, comb_tok, comb_gate, slot_of);
    gemm1_kernel<<<512, 512, 0, stream>>>(xb, w1t, comb_tok, hbuf);
    gemm2_kernel<<<256, 512, 0, stream>>>(hbuf, w2t, comb_gate, ybuf0, ybuf1);
    combine_kernel<<<TOKENS, 256, 0, stream>>>(ybuf0, ybuf1, slot_of, bias, out);
}

// Round 9
// 515.106 us; speedup vs baseline: 1.0591x; 1.0591x over previous
//
#include <hip/hip_runtime.h>
#include <stdint.h>

#define TOKENS 4096
#define HS 1024
#define FFN 4096
#define NE 8
#define CAP 512

typedef __attribute__((ext_vector_type(8))) __bf16 v8bf;
typedef __attribute__((ext_vector_type(4))) float v4f;
typedef __attribute__((ext_vector_type(8))) unsigned short v8us;
typedef __attribute__((ext_vector_type(4))) unsigned short v4us;
typedef __attribute__((ext_vector_type(4))) unsigned int v4u;

typedef __attribute__((address_space(1))) const void AS1cvoid;
typedef __attribute__((address_space(3))) void AS3void;

// round-to-nearest-even fp32 -> bf16 bits
__device__ __forceinline__ unsigned short f2bf(float f) {
    union { float f; unsigned int u; } c; c.f = f;
    unsigned int u = c.u;
    unsigned int r = (u + 0x7fffu + ((u >> 16) & 1u)) >> 16;
    return (unsigned short)r;
}

// async global->LDS, 16B per lane. LDS dest must be wave-uniform base; HW adds lane*16.
__device__ __forceinline__ void gload16(const void* g, void* l) {
    __builtin_amdgcn_global_load_lds((AS1cvoid*)g, (AS3void*)l, 16, 0, 0);
}

// ------------------------------- transpose+cvt for both weights, 4-tile pipelined
// w1: [E][HS][FFN] -> w1t [E][FFN][HS]; w2: [E][FFN][HS] -> w2t [E][HS][FFN]
// Per block: 4 consecutive 64x64 tiles (same rows, cols c0..c0+255). Tile i+1's
// global loads are issued before tile i's LDS write/read phases -> HBM latency
// hides under LDS work. Inner tile layout identical to the proven round-3 kernel.
__global__ __launch_bounds__(256) void transpose_cvt2_kernel(
    const float* __restrict__ w1, unsigned short* __restrict__ w1t,
    const float* __restrict__ w2, unsigned short* __restrict__ w2t) {
    __shared__ float tile[64][65];
    const int id = blockIdx.x;           // 4096
    const int half = id >> 11;           // 0: w1, 1: w2
    const int e = id & 7;
    const int rest = (id >> 3) & 255;    // 256 blocks per (e,half)
    int R, C, rt, ctg;
    const float* inp;
    unsigned short* outp;
    if (half == 0) { R = HS; C = FFN; rt = rest >> 4; ctg = rest & 15; inp = w1; outp = w1t; }
    else           { R = FFN; C = HS; rt = rest >> 2; ctg = rest & 3;  inp = w2; outp = w2t; }
    const size_t esz = (size_t)R * C;
    const float* ine = inp + (size_t)e * esz;
    unsigned short* oute = outp + (size_t)e * esz;
    const int r0 = rt * 64;
    const int c0base = ctg * 256;

    const int t = threadIdx.x;
    const int lc = (t & 15) * 4;
    const int lr = t >> 4;
    const int oc = t >> 2;
    const int rc = (t & 3) * 8;

    float4 cur0, cur1, cur2, cur3, nxt0, nxt1, nxt2, nxt3;
    cur0 = *(const float4*)&ine[(size_t)(r0 + lr) * C + c0base + lc];
    cur1 = *(const float4*)&ine[(size_t)(r0 + lr + 16) * C + c0base + lc];
    cur2 = *(const float4*)&ine[(size_t)(r0 + lr + 32) * C + c0base + lc];
    cur3 = *(const float4*)&ine[(size_t)(r0 + lr + 48) * C + c0base + lc];
#pragma unroll
    for (int s = 0; s < 4; ++s) {
        const int c0 = c0base + s * 64;
        if (s < 3) {   // issue next tile's loads early (hidden under LDS phases)
            nxt0 = *(const float4*)&ine[(size_t)(r0 + lr) * C + c0 + 64 + lc];
            nxt1 = *(const float4*)&ine[(size_t)(r0 + lr + 16) * C + c0 + 64 + lc];
            nxt2 = *(const float4*)&ine[(size_t)(r0 + lr + 32) * C + c0 + 64 + lc];
            nxt3 = *(const float4*)&ine[(size_t)(r0 + lr + 48) * C + c0 + 64 + lc];
        }
        tile[lr][lc] = cur0.x; tile[lr][lc + 1] = cur0.y; tile[lr][lc + 2] = cur0.z; tile[lr][lc + 3] = cur0.w;
        tile[lr + 16][lc] = cur1.x; tile[lr + 16][lc + 1] = cur1.y; tile[lr + 16][lc + 2] = cur1.z; tile[lr + 16][lc + 3] = cur1.w;
        tile[lr + 32][lc] = cur2.x; tile[lr + 32][lc + 1] = cur2.y; tile[lr + 32][lc + 2] = cur2.z; tile[lr + 32][lc + 3] = cur2.w;
        tile[lr + 48][lc] = cur3.x; tile[lr + 48][lc + 1] = cur3.y; tile[lr + 48][lc + 2] = cur3.z; tile[lr + 48][lc + 3] = cur3.w;
        __syncthreads();
#pragma unroll
        for (int i = 0; i < 2; ++i) {
            int rb = rc + 32 * i;
            v8us v;
#pragma unroll
            for (int j = 0; j < 8; ++j) v[j] = f2bf(tile[rb + j][oc]);
            *(v8us*)&oute[(size_t)(c0 + oc) * R + r0 + rb] = v;
        }
        __syncthreads();   // reads done before next tile's LDS writes
        cur0 = nxt0; cur1 = nxt1; cur2 = nxt2; cur3 = nxt3;
    }
}

// --------------------------- fused router top-2 + x->bf16 conversion (x read once)
__global__ void router_kernel(const float* __restrict__ x, const float* __restrict__ rw,
                              unsigned short* __restrict__ xb,
                              int* __restrict__ topk_e, float* __restrict__ topk_w) {
    __shared__ float rwT[NE * HS];   // rwT[e][hs]
    int tid = threadIdx.x;           // 256
    for (int i = tid; i < NE * HS; i += 256)
        rwT[(i & 7) * HS + (i >> 3)] = rw[i];
    __syncthreads();
    int lane = tid & 63, wave = tid >> 6;
    int t = blockIdx.x * 4 + wave;
    const float4* xr4 = (const float4*)(x + (size_t)t * HS);
    unsigned short* xbr = xb + (size_t)t * HS;
    float acc[NE] = {0.f, 0.f, 0.f, 0.f, 0.f, 0.f, 0.f, 0.f};
#pragma unroll
    for (int it = 0; it < 4; ++it) {
        float4 f = xr4[it * 64 + lane];
        int h0 = (it * 64 + lane) * 4;
#pragma unroll
        for (int e = 0; e < NE; ++e) {
            float4 rv = *(const float4*)&rwT[e * HS + h0];
            acc[e] += f.x * rv.x + f.y * rv.y + f.z * rv.z + f.w * rv.w;
        }
        v4us p;
        p[0] = f2bf(f.x); p[1] = f2bf(f.y); p[2] = f2bf(f.z); p[3] = f2bf(f.w);
        *(v4us*)&xbr[h0] = p;
    }
#pragma unroll
    for (int e = 0; e < NE; ++e) {
#pragma unroll
        for (int off = 32; off > 0; off >>= 1)
            acc[e] += __shfl_down(acc[e], off, 64);
    }
    if (lane == 0) {
        int b1 = 0; float v1 = acc[0];
#pragma unroll
        for (int e = 1; e < NE; ++e) if (acc[e] > v1) { v1 = acc[e]; b1 = e; }
        int b2 = -1; float v2 = -3.4e38f;
#pragma unroll
        for (int e = 0; e < NE; ++e)
            if (e != b1 && acc[e] > v2) { v2 = acc[e]; b2 = e; }
        float s = 0.f;
#pragma unroll
        for (int e = 0; e < NE; ++e) s += expf(acc[e] - v1);
        float inv = 1.f / s;
        topk_e[t * 2] = b1;
        topk_e[t * 2 + 1] = b2;
        topk_w[t * 2] = inv;
        topk_w[t * 2 + 1] = expf(v2 - v1) * inv;
    }
}

// ------------------------------------------------- dispatch: stable capped lists
// hist layout [e][tid] (stride 1056): scan reads hist[e*1056 + tid - off] are
// stride-1 across lanes -> conflict-free (old [tid*8+e] layout was 8-way).
#define HSTR 1056
__global__ void dispatch_kernel(const int* __restrict__ topk_e,
                                const float* __restrict__ topk_w,
                                int* __restrict__ comb_tok,
                                float* __restrict__ comb_gate,
                                int* __restrict__ slot_of) {
    __shared__ int hist[NE * HSTR];
    __shared__ int c0[NE];
    __shared__ int tpe_s[NE];
    const int tid = threadIdx.x;   // 1024
    for (int i = tid; i < NE * 1024; i += 1024) { comb_tok[i] = 0; comb_gate[i] = 0.f; }

    for (int k = 0; k < 2; ++k) {
        int cnt[NE];
#pragma unroll
        for (int e = 0; e < NE; ++e) cnt[e] = 0;
        int myexp[4];
#pragma unroll
        for (int j = 0; j < 4; ++j) {
            int t = tid * 4 + j;
            int ex = topk_e[t * 2 + k];
            myexp[j] = ex;
            cnt[ex]++;
        }
#pragma unroll
        for (int e = 0; e < NE; ++e) hist[e * HSTR + tid] = cnt[e];
        __syncthreads();
        for (int off = 1; off < 1024; off <<= 1) {
            int v[NE];
#pragma unroll
            for (int e = 0; e < NE; ++e) {
                v[e] = hist[e * HSTR + tid];
                if (tid >= off) v[e] += hist[e * HSTR + tid - off];
            }
            __syncthreads();
#pragma unroll
            for (int e = 0; e < NE; ++e) hist[e * HSTR + tid] = v[e];
            __syncthreads();
        }
        int base[NE];
#pragma unroll
        for (int e = 0; e < NE; ++e) base[e] = hist[e * HSTR + tid] - cnt[e];
        if (tid == 1023) {
#pragma unroll
            for (int e = 0; e < NE; ++e) tpe_s[e] = hist[e * HSTR + 1023];
        }
        __syncthreads();
        if (k == 0 && tid < NE) c0[tid] = min(tpe_s[tid], CAP);
        __syncthreads();
#pragma unroll
        for (int j = 0; j < 4; ++j) {
            int t = tid * 4 + j;
            int ex = myexp[j];
            int p = base[ex]++;
            int sl = -1;
            if (p < CAP) {
                int idx = (k == 0) ? p : (c0[ex] + p);
                sl = ex * 1024 + idx;
                comb_tok[sl] = t;
                comb_gate[sl] = topk_w[t * 2 + k];
            }
            slot_of[t * 2 + k] = sl;
        }
        __syncthreads();
    }
}

// =================================================================================
// 8-phase 256x256 BK=64 pipelined GEMM core (T2 swizzle + T3/T4 counted vmcnt + T5)
// LDS 128 KB: A0 | B0 | A1 | B1, each 256 rows x 64 cols bf16 (128 B rows).
// Swizzle: 16B chunk c of row r stored at chunk c ^ (r & 7)  (involution);
// pre-applied on the GLOBAL source (global_load_lds writes linearly), applied
// again on the read side. No sched_barrier anywhere (m141).
// =================================================================================
#define BARR __builtin_amdgcn_s_barrier()
#define LGK0 asm volatile("s_waitcnt lgkmcnt(0)" ::: "memory")
#define VMC4 asm volatile("s_waitcnt vmcnt(4)" ::: "memory")
#define VMC0 asm volatile("s_waitcnt vmcnt(0)" ::: "memory")

// region offsets: ushort index (U) and bytes (B)
#define A0U 0
#define B0U 16384
#define A1U 32768
#define B1U 49152
#define A0B 0
#define B0B 32768
#define A1B 65536
#define B1B 98304

// stage one half-tile (128 rows x 64 cols): 2 gload16 per thread, linear LDS dest
#define STAGE2(P0, P1, LBYTE, KT) do { \
    gload16((P0) + (size_t)(KT) * 64, (char*)lds + (LBYTE) + wv * 2048); \
    gload16((P1) + (size_t)(KT) * 64, (char*)lds + (LBYTE) + wv * 2048 + 1024); } while (0)

// A fragment reads: 8 x v8bf loads (compiler emits ds_read_b128)
#define PH_READ_A(REGU, MQ) do { \
    _Pragma("unroll") \
    for (int i2 = 0; i2 < 4; ++i2) { \
        a[i2][0] = *(const v8bf*)&lds[(REGU) + arow + (MQ) * 4096 + i2 * 1024 + axk0]; \
        a[i2][1] = *(const v8bf*)&lds[(REGU) + arow + (MQ) * 4096 + i2 * 1024 + axk1]; \
    } } while (0)

// B fragment reads: 4 x v8bf loads
#define PH_READ_B(REGU, NQ) do { \
    _Pragma("unroll") \
    for (int j2 = 0; j2 < 2; ++j2) { \
        b[(NQ) * 2 + j2][0] = *(const v8bf*)&lds[(REGU) + brow + ((NQ) * 2 + j2) * 1024 + axk0]; \
        b[(NQ) * 2 + j2][1] = *(const v8bf*)&lds[(REGU) + brow + ((NQ) * 2 + j2) * 1024 + axk1]; \
    } } while (0)

#define PH_MFMA(MQ, NQ) do { \
    __builtin_amdgcn_s_setprio(1); \
    _Pragma("unroll") \
    for (int ks = 0; ks < 2; ++ks) \
    _Pragma("unroll") \
    for (int i2 = 0; i2 < 4; ++i2) \
    _Pragma("unroll") \
    for (int j2 = 0; j2 < 2; ++j2) \
        acc[(MQ) * 4 + i2][(NQ) * 2 + j2] = __builtin_amdgcn_mfma_f32_16x16x32_bf16( \
            a[i2][ks], b[(NQ) * 2 + j2][ks], acc[(MQ) * 4 + i2][(NQ) * 2 + j2], 0, 0, 0); \
    __builtin_amdgcn_s_setprio(0); } while (0)

// vmcnt ledger: 12 in flight at each VMC4 -> waits for the oldest 8 (the two
// half-tile pairs consumed in the next 4 phases), leaves newest 4 in flight.
#define MOE_PIPE(NITER_) do { \
    STAGE2(pA00, pA01, A0B, 0); \
    STAGE2(pA10, pA11, A0B + 16384, 0); \
    STAGE2(pB00, pB01, B0B, 0); \
    STAGE2(pB10, pB11, B0B + 16384, 0); \
    STAGE2(pB00, pB01, B1B, 1); \
    STAGE2(pB10, pB11, B1B + 16384, 1); \
    VMC4; BARR; \
    for (int t = 0; t < (NITER_); ++t) { \
        const int T1k = 2 * t + 1, T2k = 2 * t + 2, T3k = 2 * t + 3; \
        const bool more = (t + 1 < (NITER_)); \
        PH_READ_A(A0U, 0); PH_READ_B(B0U, 0); \
        STAGE2(pA00, pA01, A1B, T1k); \
        BARR; LGK0; PH_MFMA(0, 0); BARR; \
        PH_READ_B(B0U, 1); \
        STAGE2(pA10, pA11, A1B + 16384, T1k); \
        BARR; LGK0; PH_MFMA(0, 1); BARR; \
        PH_READ_A(A0U, 1); \
        if (more) STAGE2(pB00, pB01, B0B, T2k); \
        BARR; LGK0; PH_MFMA(1, 0); BARR; \
        if (more) { STAGE2(pB10, pB11, B0B + 16384, T2k); VMC4; } else { VMC0; } \
        BARR; PH_MFMA(1, 1); BARR; \
        PH_READ_A(A1U, 0); PH_READ_B(B1U, 0); \
        if (more) STAGE2(pA00, pA01, A0B, T2k); \
        BARR; LGK0; PH_MFMA(0, 0); BARR; \
        PH_READ_B(B1U, 1); \
        if (more) STAGE2(pA10, pA11, A0B + 16384, T2k); \
        BARR; LGK0; PH_MFMA(0, 1); BARR; \
        PH_READ_A(A1U, 1); \
        if (more) STAGE2(pB00, pB01, B1B, T3k); \
        BARR; LGK0; PH_MFMA(1, 0); BARR; \
        if (more) { STAGE2(pB10, pB11, B1B + 16384, T3k); VMC4; } else { VMC0; } \
        BARR; PH_MFMA(1, 1); BARR; \
    } } while (0)

// ------------------------------------------------- GEMM1: h = gelu(gather(x) @ W1e)
// grid 512: id&7 = expert (XCD-affine); rest: mt 0..3 (slot/256), nt 0..15 (ffn/256)
__global__ __launch_bounds__(512, 2) void gemm1_kernel(
    const unsigned short* __restrict__ xb,      // [TOKENS][HS] bf16
    const unsigned short* __restrict__ w1t,     // [E][FFN][HS] bf16
    const int* __restrict__ comb_tok,           // [E][1024]
    unsigned short* __restrict__ h)             // [E][1024][FFN] bf16
{
    __shared__ __align__(16) unsigned short lds[65536];   // 128 KB
    const int id = blockIdx.x;
    const int e = id & 7;
    const int rest = id >> 3;
    const int mt = rest & 3;
    const int nt = rest >> 2;          // 0..15
    const int tid = threadIdx.x;
    const int wv = tid >> 6;           // wave 0..7
    const int l = tid & 63;
    const int m = l & 15;
    const int quad = l >> 4;
    const int wr = wv >> 2;            // 0..1 -> 128 rows
    const int wc = wv & 3;             // 0..3 -> 64 cols
    const int l3 = l >> 3;             // 0..7
    const int cgs = ((l & 7) ^ l3) * 8;   // pre-swizzled global chunk (elems)

    // staging rows (within 256-row tile): r(h,j) = h*128 + wv*16 + j*8 + l3
    const int r00 = wv * 16 + l3, r01 = r00 + 8, r10 = r00 + 128, r11 = r01 + 128;
    const int tbase = e * 1024 + mt * 256;
    const unsigned short* pA00 = xb + (size_t)comb_tok[tbase + r00] * HS + cgs;
    const unsigned short* pA01 = xb + (size_t)comb_tok[tbase + r01] * HS + cgs;
    const unsigned short* pA10 = xb + (size_t)comb_tok[tbase + r10] * HS + cgs;
    const unsigned short* pA11 = xb + (size_t)comb_tok[tbase + r11] * HS + cgs;
    const unsigned short* wbp = w1t + (size_t)e * FFN * HS + (size_t)(nt * 256) * HS + cgs;
    const unsigned short* pB00 = wbp + (size_t)r00 * HS;
    const unsigned short* pB01 = wbp + (size_t)r01 * HS;
    const unsigned short* pB10 = wbp + (size_t)r10 * HS;
    const unsigned short* pB11 = wbp + (size_t)r11 * HS;

    // fragment-read bases (ushort idx within region) + swizzled chunk offsets
    const int arow = (wr * 128 + m) * 64;
    const int brow = (wc * 64 + m) * 64;
    const int axk0 = (quad ^ (m & 7)) * 8;
    const int axk1 = ((quad + 4) ^ (m & 7)) * 8;

    v4f acc[8][4];
#pragma unroll
    for (int i = 0; i < 8; ++i)
#pragma unroll
        for (int j = 0; j < 4; ++j) acc[i][j] = (v4f)(0.f);
    v8bf a[4][2], b[4][2];

    MOE_PIPE(8);   // 16 K-tiles of 64 (K = HS = 1024)

    // epilogue: gelu -> per-wave swizzled LDS repack -> 16B global stores
    unsigned short* us = lds + wv * 8192;    // 128x64 bf16 slice per wave
#pragma unroll
    for (int i = 0; i < 8; ++i)
#pragma unroll
        for (int j = 0; j < 4; ++j) {
            v4f v = acc[i][j];
#pragma unroll
            for (int r = 0; r < 4; ++r) {
                int row = i * 16 + quad * 4 + r;
                int col = j * 16 + m;
                float val = v[r];
                float inner = 0.7978845608028654f * (val + 0.044715f * val * val * val);
                float g = val / (1.f + __expf(-2.f * inner));   // val*sigmoid(2*inner)
                us[row * 64 + (((col >> 3) ^ (row & 7)) * 8) + (col & 7)] = f2bf(g);
            }
        }
    __syncthreads();
    unsigned short* hb = h + (size_t)e * 1024 * FFN + (size_t)(mt * 256 + wr * 128) * FFN
                         + nt * 256 + wc * 64;
    const int chl = l & 7;
#pragma unroll
    for (int p = 0; p < 16; ++p) {
        int row = p * 8 + l3;
        v8us v = *(const v8us*)&us[row * 64 + ((chl ^ l3) * 8)];
        *(v8us*)&hb[(size_t)row * FFN + chl * 8] = v;
    }
}

// ------------------------------------------------- GEMM2: y_ks[slot] = gate * (h @ W2e)_Khalf
// grid 256: id&7 = expert (XCD-affine); rest: mt 0..3, nt 0..3, ks 0..1 (split-K)
__global__ __launch_bounds__(512, 2) void gemm2_kernel(
    const unsigned short* __restrict__ hbuf,    // [E][1024][FFN] bf16
    const unsigned short* __restrict__ w2t,     // [E][HS][FFN] bf16
    const float* __restrict__ comb_gate,
    float* __restrict__ y0,                     // [E*1024][HS] fp32 (K half 0)
    float* __restrict__ y1)                     // [E*1024][HS] fp32 (K half 1)
{
    __shared__ __align__(16) unsigned short lds[65536];   // 128 KB
    const int id = blockIdx.x;
    const int e = id & 7;
    const int rest = id >> 3;
    const int mt = rest & 3;
    const int nt = (rest >> 2) & 3;
    const int ks = rest >> 4;
    const int tid = threadIdx.x;
    const int wv = tid >> 6;
    const int l = tid & 63;
    const int m = l & 15;
    const int quad = l >> 4;
    const int wr = wv >> 2;
    const int wc = wv & 3;
    const int l3 = l >> 3;
    const int cgs = ((l & 7) ^ l3) * 8;

    const int r00 = wv * 16 + l3, r01 = r00 + 8, r10 = r00 + 128, r11 = r01 + 128;
    const unsigned short* ha = hbuf + (size_t)e * 1024 * FFN + (size_t)(mt * 256) * FFN
                               + ks * 2048 + cgs;
    const unsigned short* pA00 = ha + (size_t)r00 * FFN;
    const unsigned short* pA01 = ha + (size_t)r01 * FFN;
    const unsigned short* pA10 = ha + (size_t)r10 * FFN;
    const unsigned short* pA11 = ha + (size_t)r11 * FFN;
    const unsigned short* wbp = w2t + (size_t)e * HS * FFN + (size_t)(nt * 256) * FFN
                                + ks * 2048 + cgs;
    const unsigned short* pB00 = wbp + (size_t)r00 * FFN;
    const unsigned short* pB01 = wbp + (size_t)r01 * FFN;
    const unsigned short* pB10 = wbp + (size_t)r10 * FFN;
    const unsigned short* pB11 = wbp + (size_t)r11 * FFN;

    const int arow = (wr * 128 + m) * 64;
    const int brow = (wc * 64 + m) * 64;
    const int axk0 = (quad ^ (m & 7)) * 8;
    const int axk1 = ((quad + 4) ^ (m & 7)) * 8;

    v4f acc[8][4];
#pragma unroll
    for (int i = 0; i < 8; ++i)
#pragma unroll
        for (int j = 0; j < 4; ++j) acc[i][j] = (v4f)(0.f);
    v8bf a[4][2], b[4][2];

    MOE_PIPE(16);   // 32 K-tiles of 64 (K half = 2048)

    // epilogue: gated fp32 stores (64B segments per 16-lane group)
    float* yb = (ks ? y1 : y0) + (size_t)e * 1024 * HS;
    const int rbase = mt * 256 + wr * 128;
    const int cbase = nt * 256 + wc * 64;
#pragma unroll
    for (int i = 0; i < 8; ++i) {
        float gate_r[4];
        int row_r[4];
#pragma unroll
        for (int r = 0; r < 4; ++r) {
            row_r[r] = rbase + i * 16 + quad * 4 + r;
            gate_r[r] = comb_gate[e * 1024 + row_r[r]];
        }
#pragma unroll
        for (int j = 0; j < 4; ++j) {
            v4f v = acc[i][j];
#pragma unroll
            for (int r = 0; r < 4; ++r)
                yb[(size_t)row_r[r] * HS + cbase + j * 16 + m] = gate_r[r] * v[r];
        }
    }
}

// --------------------------- combine: out = bias + sum over k,ks of y_ks[slot_k]
__global__ void combine_kernel(const float* __restrict__ y0, const float* __restrict__ y1,
                               const int* __restrict__ slot_of,
                               const float* __restrict__ bias,
                               float* __restrict__ out) {
    int t = blockIdx.x;            // token
    int c = threadIdx.x;           // float4 lane, 256
    const float4* y04 = (const float4*)y0;
    const float4* y14 = (const float4*)y1;
    float4 a = ((const float4*)bias)[c];
    int s0 = slot_of[t * 2];
    int s1 = slot_of[t * 2 + 1];
    if (s0 >= 0) {
        float4 u = y04[(size_t)s0 * 256 + c];
        float4 v = y14[(size_t)s0 * 256 + c];
        a.x += u.x + v.x; a.y += u.y + v.y; a.z += u.z + v.z; a.w += u.w + v.w;
    }
    if (s1 >= 0) {
        float4 u = y04[(size_t)s1 * 256 + c];
        float4 v = y14[(size_t)s1 * 256 + c];
        a.x += u.x + v.x; a.y += u.y + v.y; a.z += u.z + v.z; a.w += u.w + v.w;
    }
    ((float4*)out)[(size_t)t * 256 + c] = a;
}

// ---------------------------------------------------------------------- launch
extern "C" void kernel_launch(void* const* d_in, const int* in_sizes, int n_in,
                              void* d_out, int out_size, void* d_ws, size_t ws_size,
                              hipStream_t stream) {
    (void)in_sizes; (void)n_in; (void)out_size; (void)ws_size;
    const float* x    = (const float*)d_in[0];
    const float* rw   = (const float*)d_in[1];
    const float* w1   = (const float*)d_in[2];
    const float* w2   = (const float*)d_in[3];
    const float* bias = (const float*)d_in[4];
    float* out = (float*)d_out;

    char* p = (char*)d_ws;
    unsigned short* w1t  = (unsigned short*)p; p += (size_t)NE * FFN * HS * 2;   // 64 MB (dead after gemm1)
    unsigned short* w2t  = (unsigned short*)p; p += (size_t)NE * HS * FFN * 2;   // 64 MB
    unsigned short* xb   = (unsigned short*)p; p += (size_t)TOKENS * HS * 2;     // 8 MB
    unsigned short* hbuf = (unsigned short*)p; p += (size_t)NE * 1024 * FFN * 2; // 64 MB
    float* ybuf0     = (float*)p; p += (size_t)NE * 1024 * HS * 4;               // 32 MB
    int*   topk_e    = (int*)p;   p += (size_t)TOKENS * 2 * 4;
    float* topk_w    = (float*)p; p += (size_t)TOKENS * 2 * 4;
    int*   comb_tok  = (int*)p;   p += (size_t)NE * 1024 * 4;
    float* comb_gate = (float*)p; p += (size_t)NE * 1024 * 4;
    int*   slot_of   = (int*)p;   p += (size_t)TOKENS * 2 * 4;
    float* ybuf1 = (float*)w1t;   // alias: w1t dead once gemm1 completes

    transpose_cvt2_kernel<<<4096, 256, 0, stream>>>(w1, w1t, w2, w2t);
    router_kernel<<<TOKENS / 4, 256, 0, stream>>>(x, rw, xb, topk_e, topk_w);
    dispatch_kernel<<<1, 1024, 0, stream>>>(topk_e, topk_w, comb_tok, comb_gate, slot_of);
    gemm1_kernel<<<512, 512, 0, stream>>>(xb, w1t, comb_tok, hbuf);
    gemm2_kernel<<<256, 512, 0, stream>>>(hbuf, w2t, comb_gate, ybuf0, ybuf1);
    combine_kernel<<<TOKENS, 256, 0, stream>>>(ybuf0, ybuf1, slot_of, bias, out);
}